// Round 12
// baseline (71.572 us; speedup 1.0000x reference)
//
#include <hip/hip_runtime.h>
#include <math.h>

#define NROWS 8192
#define DIM 64
#define KNBR 200
#define NSLICE 8
#define SLICE_ROWS 12500      // 100000 / 8; one slice = 3.2 MB, fits XCD L2
#define RPB 32                // rows per gather block
#define MROWS 8               // rows per MLP wave
#define MLP_BLOCKS 256        // 8192 / (4 waves * 8 rows)
#define GATHER_BLOCKS (NROWS / RPB * NSLICE)   // 256*8 = 2048
#define BN_EPS 1e-5f
#define BIGF 3.402823466e38f

__device__ __forceinline__ float d2part(const float4 a, const float4 b) {
    const float dx = a.x - b.x, dy = a.y - b.y, dz = a.z - b.z, dw = a.w - b.w;
    float d2 = dx * dx;
    d2 = fmaf(dy, dy, d2);
    d2 = fmaf(dz, dz, d2);
    d2 = fmaf(dw, dw, d2);
    return d2;
}

// 8-row register-blocked matvec: out[r][lane] = sum_i X[r][xoff+i] * W[i*64+lane]
// Each W element loaded ONCE per wave, FMA'd against all 8 rows.
__device__ __forceinline__ void mv8(const float* X, int xoff,
                                    const float* __restrict__ W,
                                    int lane, float* acc, int in4) {
#pragma unroll
    for (int r = 0; r < MROWS; ++r) acc[r] = 0.f;
    for (int i4 = 0; i4 < in4; ++i4) {
        const float w0 = W[(i4 * 4 + 0) * 64 + lane];
        const float w1 = W[(i4 * 4 + 1) * 64 + lane];
        const float w2 = W[(i4 * 4 + 2) * 64 + lane];
        const float w3 = W[(i4 * 4 + 3) * 64 + lane];
#pragma unroll
        for (int r = 0; r < MROWS; ++r) {
            const float4 xv = *(const float4*)&X[r * 132 + xoff + i4 * 4];
            acc[r] = fmaf(xv.x, w0, acc[r]);
            acc[r] = fmaf(xv.y, w1, acc[r]);
            acc[r] = fmaf(xv.z, w2, acc[r]);
            acc[r] = fmaf(xv.w, w3, acc[r]);
        }
    }
}

// ---------- kernel 1: bin neighbors by slice + stage dense query rows ----------
__global__ __launch_bounds__(256) void bin_rows(
    const float* __restrict__ v_embed,
    const int* __restrict__ nodes_v,
    const int* __restrict__ nbr_idx, const int* __restrict__ nbr_len,
    int* __restrict__ ws_list, int* __restrict__ ws_cnt,
    int* __restrict__ ws_off, float* __restrict__ ws_q) {
    const int w = threadIdx.x >> 6;
    const int lane = threadIdx.x & 63;
    const int row = blockIdx.x * 4 + w;

    __shared__ int cnt[4][NSLICE];
    __shared__ int off[4][NSLICE];

    if (lane < NSLICE) cnt[w][lane] = 0;
    __syncthreads();

    const int node = nodes_v[row];
    if (lane < 16) {
        const float4 vq = ((const float4*)(v_embed + ((size_t)node << 6)))[lane];
        ((float4*)(ws_q + (size_t)row * DIM))[lane] = vq;
    }

    int len = nbr_len[row];
    if (len < 1) len = 1;
    const int* nb = nbr_idx + (size_t)row * KNBR;

    int myidx[4], myslice[4], mypos[4];
#pragma unroll
    for (int t = 0; t < 4; ++t) {
        const int k = t * 64 + lane;
        const bool v = k < len;
        const int idx = v ? nb[k] : 0;
        const int s = idx / SLICE_ROWS;
        myidx[t] = idx;
        myslice[t] = s;
        mypos[t] = v ? atomicAdd(&cnt[w][s], 1) : 0;
    }
    __syncthreads();
    if (lane == 0) {
        int acc = 0;
#pragma unroll
        for (int s = 0; s < NSLICE; ++s) { off[w][s] = acc; acc += cnt[w][s]; }
    }
    __syncthreads();
#pragma unroll
    for (int t = 0; t < 4; ++t) {
        const int k = t * 64 + lane;
        if (k < len) {
            ws_list[(size_t)row * KNBR + off[w][myslice[t]] + mypos[t]] = myidx[t];
        }
    }
    if (lane < NSLICE) {
        ws_cnt[row * NSLICE + lane] = cnt[w][lane];
        ws_off[row * NSLICE + lane] = off[w][lane];
    }
}

// ---------- kernel 2: heterogeneous main ----------
// blockIdx < MLP_BLOCKS: register-blocked MLP (8 rows/wave, W amortized 8x).
// else: GATHER -- slice s = (blockIdx-MLP_BLOCKS)&7 (MLP_BLOCKS % 8 == 0 keeps
//   the blockIdx%8 -> XCD alignment; R10 confirmed FETCH 96->37MB). 32 rows x
//   1 slice per block; 4 rows concurrent per wave; 8 gathers in flight.
__global__ __launch_bounds__(256) void fused_main(
    const float* __restrict__ v_embed,
    const float* __restrict__ u1p, const float* __restrict__ u2p,
    const float* __restrict__ u3p, const float* __restrict__ u4p,
    const float* __restrict__ evp,
    const float* __restrict__ w_ur1, const float* __restrict__ b_ur1,
    const float* __restrict__ w_ur2, const float* __restrict__ b_ur2,
    const float* __restrict__ w_vr1, const float* __restrict__ b_vr1,
    const float* __restrict__ w_vr2, const float* __restrict__ b_vr2,
    const float* __restrict__ w_uv1, const float* __restrict__ b_uv1,
    const float* __restrict__ w_uv2, const float* __restrict__ b_uv2,
    const float* __restrict__ w_uv3, const float* __restrict__ b_uv3,
    const float* __restrict__ bn1_g, const float* __restrict__ bn1_b,
    const float* __restrict__ bn1_m, const float* __restrict__ bn1_v,
    const float* __restrict__ bn2_g, const float* __restrict__ bn2_b,
    const float* __restrict__ bn2_m, const float* __restrict__ bn2_v,
    const float* __restrict__ bn3_g, const float* __restrict__ bn3_b,
    const float* __restrict__ bn3_m, const float* __restrict__ bn3_v,
    const float* __restrict__ bn4_g, const float* __restrict__ bn4_b,
    const float* __restrict__ bn4_m, const float* __restrict__ bn4_v,
    const int* __restrict__ ws_list, const int* __restrict__ ws_cnt,
    const int* __restrict__ ws_off, const float* __restrict__ ws_q,
    float* __restrict__ out_score, float* __restrict__ ws_d2p,
    float* __restrict__ ws_c) {
    const int w = threadIdx.x >> 6;
    const int lane = threadIdx.x & 63;

    __shared__ float xsbuf[4][MROWS][132];   // 16.9 KB (MLP path)
    __shared__ int scnt[RPB];
    __shared__ int soff[RPB];

    if (blockIdx.x >= MLP_BLOCKS) {
        // ================= GATHER: 32 rows x slice s =================
        const int gb = blockIdx.x - MLP_BLOCKS;
        const int s = gb & 7;                // == this block's XCD
        const int row0 = (gb >> 3) * RPB;

        if (threadIdx.x < RPB) {
            scnt[threadIdx.x] = ws_cnt[(row0 + threadIdx.x) * NSLICE + s];
            soff[threadIdx.x] = ws_off[(row0 + threadIdx.x) * NSLICE + s];
        }
        __syncthreads();

        const int riq = lane >> 4;           // row within quad-group (0..3)
        const int slot = (lane >> 2) & 3;    // neighbor slot (0..3)
        const int sub = lane & 3;            // quad sub-lane (0..3)

#pragma unroll
        for (int qg = 0; qg < 2; ++qg) {
            const int lr = w * 8 + qg * 4 + riq;
            const int row = row0 + lr;
            const int cnt = scnt[lr];
            float dmin2 = BIGF;
            if (cnt > 0) {
                const int off = soff[lr];
                const float4* qr = (const float4*)(ws_q + (size_t)row * DIM);
                const float4 q0 = qr[sub + 0];
                const float4 q1 = qr[sub + 4];
                const float4 q2 = qr[sub + 8];
                const float4 q3 = qr[sub + 12];
                const int* lst = ws_list + (size_t)row * KNBR + off;
                const int cm1 = cnt - 1;
                for (int j0 = 0; j0 < cnt; j0 += 8) {
                    int ja = j0 + slot;        ja = ja < cm1 ? ja : cm1;
                    int jb = j0 + 4 + slot;    jb = jb < cm1 ? jb : cm1;
                    const int ia = lst[ja];
                    const int ib = lst[jb];
                    const float4* ra = (const float4*)(v_embed + ((size_t)ia << 6));
                    const float4* rb = (const float4*)(v_embed + ((size_t)ib << 6));
                    const float4 a0 = ra[sub + 0], a1 = ra[sub + 4];
                    const float4 a2 = ra[sub + 8], a3 = ra[sub + 12];
                    const float4 c0 = rb[sub + 0], c1 = rb[sub + 4];
                    const float4 c2 = rb[sub + 8], c3 = rb[sub + 12];
                    float da = d2part(q0, a0) + d2part(q1, a1)
                             + d2part(q2, a2) + d2part(q3, a3);
                    float db = d2part(q0, c0) + d2part(q1, c1)
                             + d2part(q2, c2) + d2part(q3, c3);
                    da += __shfl_xor(da, 1); da += __shfl_xor(da, 2);
                    db += __shfl_xor(db, 1); db += __shfl_xor(db, 2);
                    dmin2 = fminf(dmin2, fminf(da, db));
                }
            }
            dmin2 = fminf(dmin2, __shfl_xor(dmin2, 4));
            dmin2 = fminf(dmin2, __shfl_xor(dmin2, 8));
            if ((lane & 15) == 0) ws_d2p[row * NSLICE + s] = dmin2;
        }
        return;
    }

    // ================= MLP: 8 rows per wave, W amortized =================
    const int mrow0 = (blockIdx.x * 4 + w) * MROWS;
    float* X = &xsbuf[w][0][0];              // [8][132]

    // fold BN+bias to per-lane scale/offset (computed once per wave)
    const float s1v = rsqrtf(bn1_v[lane] + BN_EPS) * bn1_g[lane];
    const float o1v = bn1_b[lane] + (b_ur1[lane] - bn1_m[lane]) * s1v;
    const float s2v = rsqrtf(bn2_v[lane] + BN_EPS) * bn2_g[lane];
    const float o2v = bn2_b[lane] + (b_vr1[lane] - bn2_m[lane]) * s2v;
    const float s3v = rsqrtf(bn3_v[lane] + BN_EPS) * bn3_g[lane];
    const float o3v = bn3_b[lane] + (b_uv1[lane] - bn3_m[lane]) * s3v;
    const int col = lane & 15;
    const int q = lane >> 4;
    const float s4v = rsqrtf(bn4_v[col] + BN_EPS) * bn4_g[col];
    const float o4v = bn4_b[col] + (b_uv2[col] - bn4_m[col]) * s4v;
    const float w3c = w_uv3[col];
    const float b3 = b_uv3[0];
    const float bu2 = b_ur2[lane];
    const float bv2 = b_vr2[lane];

    // phase A: embeds + curiosity; stage eu (first half) and ev (second half)
#pragma unroll 2
    for (int r = 0; r < MROWS; ++r) {
        const int row = mrow0 + r;
        const size_t rb = (size_t)row * DIM + lane;
        const float u1 = u1p[rb], u2 = u2p[rb], u3 = u3p[rb], u4 = u4p[rb];
        const float ev = evp[rb];
        float d12 = u1 - u2, d23 = u2 - u3, d34 = u3 - u4;
        float s1 = d12 * d12, s2 = d23 * d23, s3 = d34 * d34;
#pragma unroll
        for (int m = 1; m < 64; m <<= 1) {
            s1 += __shfl_xor(s1, m);
            s2 += __shfl_xor(s2, m);
            s3 += __shfl_xor(s3, m);
        }
        if (lane == 0) {
            ws_c[row] = (sqrtf(s1) + sqrtf(s2) + sqrtf(s3)) * (1.0f / 3.0f);
        }
        float eu = u1 * 0.032058603280084993f;
        eu = fmaf(u2, 0.087144318742032567f, eu);
        eu = fmaf(u3, 0.236882818089910134f, eu);
        eu = fmaf(u4, 0.643914259887972245f, eu);
        X[r * 132 + lane] = eu;
        X[r * 132 + 64 + lane] = ev;
    }

    float acc[MROWS];
    // V branch layer 1 (reads+rewrites second half; ev consumed)
    mv8(X, 64, w_vr1, lane, acc, 16);
#pragma unroll
    for (int r = 0; r < MROWS; ++r)
        X[r * 132 + 64 + lane] = fmaxf(fmaf(acc[r], s2v, o2v), 0.f);
    // V branch layer 2 -> xv lands in concat position [64..128)
    mv8(X, 64, w_vr2, lane, acc, 16);
#pragma unroll
    for (int r = 0; r < MROWS; ++r)
        X[r * 132 + 64 + lane] = acc[r] + bv2;
    // U branch layer 1 (first half)
    mv8(X, 0, w_ur1, lane, acc, 16);
#pragma unroll
    for (int r = 0; r < MROWS; ++r)
        X[r * 132 + lane] = fmaxf(fmaf(acc[r], s1v, o1v), 0.f);
    // U branch layer 2 -> xu lands in concat position [0..64)
    mv8(X, 0, w_ur2, lane, acc, 16);
#pragma unroll
    for (int r = 0; r < MROWS; ++r)
        X[r * 132 + lane] = acc[r] + bu2;
    // uv1: 128 -> 64
    mv8(X, 0, w_uv1, lane, acc, 32);
#pragma unroll
    for (int r = 0; r < MROWS; ++r)
        X[r * 132 + lane] = fmaxf(fmaf(acc[r], s3v, o3v), 0.f);

    // uv2: 64 -> 16 (quartered over lanes: q = i-range, col = output)
    float acc2[MROWS];
#pragma unroll
    for (int r = 0; r < MROWS; ++r) acc2[r] = 0.f;
#pragma unroll
    for (int i4 = 0; i4 < 4; ++i4) {
        const int ii = q * 16 + i4 * 4;
        const float v0 = w_uv2[(ii + 0) * 16 + col];
        const float v1 = w_uv2[(ii + 1) * 16 + col];
        const float v2 = w_uv2[(ii + 2) * 16 + col];
        const float v3 = w_uv2[(ii + 3) * 16 + col];
#pragma unroll
        for (int r = 0; r < MROWS; ++r) {
            const float4 xv = *(const float4*)&X[r * 132 + ii];
            acc2[r] = fmaf(xv.x, v0, acc2[r]);
            acc2[r] = fmaf(xv.y, v1, acc2[r]);
            acc2[r] = fmaf(xv.z, v2, acc2[r]);
            acc2[r] = fmaf(xv.w, v3, acc2[r]);
        }
    }
#pragma unroll
    for (int r = 0; r < MROWS; ++r) {
        float a = acc2[r];
        a += __shfl_xor(a, 16);
        a += __shfl_xor(a, 32);                    // full pre-BN h4[col]
        const float h = fmaxf(fmaf(a, s4v, o4v), 0.f);
        float p = h * w3c;
        p += __shfl_xor(p, 1);
        p += __shfl_xor(p, 2);
        p += __shfl_xor(p, 4);
        p += __shfl_xor(p, 8);                     // sum over 16 cols
        if (lane == 0) out_score[mrow0 + r] = p + b3;
    }
}

// ---------- final combine: fold slice partials + global min/max + outputs ----------
__global__ __launch_bounds__(1024) void combine(
    const float* __restrict__ ws_d2p, const float* __restrict__ ws_c,
    float* __restrict__ out) {
    const int tid = threadIdx.x;
    __shared__ float red[4][16];

    float ld2[8], lc[8];
    float dmin = BIGF, dmax = -BIGF, cmin = BIGF, cmax = -BIGF;
#pragma unroll
    for (int i = 0; i < 8; ++i) {
        const int b = tid * 8 + i;  // 1024 * 8 == 8192
        float m = ws_d2p[b * NSLICE];
#pragma unroll
        for (int s = 1; s < NSLICE; ++s) m = fminf(m, ws_d2p[b * NSLICE + s]);
        ld2[i] = m;
        lc[i] = ws_c[b];
        dmin = fminf(dmin, m);
        dmax = fmaxf(dmax, m);
        cmin = fminf(cmin, lc[i]);
        cmax = fmaxf(cmax, lc[i]);
    }
#pragma unroll
    for (int m = 1; m < 64; m <<= 1) {
        dmin = fminf(dmin, __shfl_xor(dmin, m));
        dmax = fmaxf(dmax, __shfl_xor(dmax, m));
        cmin = fminf(cmin, __shfl_xor(cmin, m));
        cmax = fmaxf(cmax, __shfl_xor(cmax, m));
    }
    const int wid = tid >> 6;
    const int lane = tid & 63;
    if (lane == 0) {
        red[0][wid] = dmin;
        red[1][wid] = dmax;
        red[2][wid] = cmin;
        red[3][wid] = cmax;
    }
    __syncthreads();
    dmin = red[0][0]; dmax = red[1][0]; cmin = red[2][0]; cmax = red[3][0];
#pragma unroll
    for (int i = 1; i < 16; ++i) {
        dmin = fminf(dmin, red[0][i]);
        dmax = fmaxf(dmax, red[1][i]);
        cmin = fminf(cmin, red[2][i]);
        cmax = fmaxf(cmax, red[3][i]);
    }
    const float dlo = sqrtf(dmin);
    const float dhi = sqrtf(dmax);
    const float inv_d = 1.f / (dhi - dlo);
    const float inv_c = 1.f / (cmax - cmin);
#pragma unroll
    for (int i = 0; i < 8; ++i) {
        const int b = tid * 8 + i;
        const float t = (sqrtf(ld2[i]) - dlo) * inv_d;
        const float unexp = 6.f * t * expf(-6.f * t);
        out[b] += unexp * (lc[i] - cmin) * inv_c;
    }
}

extern "C" void kernel_launch(void* const* d_in, const int* in_sizes, int n_in,
                              void* d_out, int out_size, void* d_ws, size_t ws_size,
                              hipStream_t stream) {
    const float* v_embed = (const float*)d_in[0];
    const float* u1 = (const float*)d_in[1];
    const float* u2 = (const float*)d_in[2];
    const float* u3 = (const float*)d_in[3];
    const float* u4 = (const float*)d_in[4];
    const float* ev = (const float*)d_in[5];
    const float* w_ur1 = (const float*)d_in[6];
    const float* b_ur1 = (const float*)d_in[7];
    const float* w_ur2 = (const float*)d_in[8];
    const float* b_ur2 = (const float*)d_in[9];
    const float* w_vr1 = (const float*)d_in[10];
    const float* b_vr1 = (const float*)d_in[11];
    const float* w_vr2 = (const float*)d_in[12];
    const float* b_vr2 = (const float*)d_in[13];
    const float* w_uv1 = (const float*)d_in[14];
    const float* b_uv1 = (const float*)d_in[15];
    const float* w_uv2 = (const float*)d_in[16];
    const float* b_uv2 = (const float*)d_in[17];
    const float* w_uv3 = (const float*)d_in[18];
    const float* b_uv3 = (const float*)d_in[19];
    const int* nodes_v = (const int*)d_in[20];
    const int* nbr_idx = (const int*)d_in[21];
    const int* nbr_len = (const int*)d_in[22];
    const float* bn1_g = (const float*)d_in[23];
    const float* bn1_b = (const float*)d_in[24];
    const float* bn1_m = (const float*)d_in[25];
    const float* bn1_v = (const float*)d_in[26];
    const float* bn2_g = (const float*)d_in[27];
    const float* bn2_b = (const float*)d_in[28];
    const float* bn2_m = (const float*)d_in[29];
    const float* bn2_v = (const float*)d_in[30];
    const float* bn3_g = (const float*)d_in[31];
    const float* bn3_b = (const float*)d_in[32];
    const float* bn3_m = (const float*)d_in[33];
    const float* bn3_v = (const float*)d_in[34];
    const float* bn4_g = (const float*)d_in[35];
    const float* bn4_b = (const float*)d_in[36];
    const float* bn4_m = (const float*)d_in[37];
    const float* bn4_v = (const float*)d_in[38];

    float* out = (float*)d_out;
    int* ws_list = (int*)d_ws;                         // NROWS*KNBR ints
    int* ws_cnt = ws_list + (size_t)NROWS * KNBR;      // NROWS*8
    int* ws_off = ws_cnt + NROWS * NSLICE;             // NROWS*8
    float* ws_d2p = (float*)(ws_off + NROWS * NSLICE); // NROWS*8
    float* ws_c = ws_d2p + NROWS * NSLICE;             // NROWS
    float* ws_q = ws_c + NROWS;                        // NROWS*DIM

    hipLaunchKernelGGL(bin_rows, dim3(NROWS / 4), dim3(256), 0, stream,
                       v_embed, nodes_v, nbr_idx, nbr_len,
                       ws_list, ws_cnt, ws_off, ws_q);
    hipLaunchKernelGGL(fused_main, dim3(MLP_BLOCKS + GATHER_BLOCKS), dim3(256), 0, stream,
                       v_embed, u1, u2, u3, u4, ev,
                       w_ur1, b_ur1, w_ur2, b_ur2, w_vr1, b_vr1, w_vr2, b_vr2,
                       w_uv1, b_uv1, w_uv2, b_uv2, w_uv3, b_uv3,
                       bn1_g, bn1_b, bn1_m, bn1_v,
                       bn2_g, bn2_b, bn2_m, bn2_v,
                       bn3_g, bn3_b, bn3_m, bn3_v,
                       bn4_g, bn4_b, bn4_m, bn4_v,
                       ws_list, ws_cnt, ws_off, ws_q,
                       out, ws_d2p, ws_c);
    hipLaunchKernelGGL(combine, dim3(1), dim3(1024), 0, stream,
                       ws_d2p, ws_c, out);
}